// Round 1
// baseline (1739.024 us; speedup 1.0000x reference)
//
#include <hip/hip_runtime.h>
#include <math.h>

// ---------------- problem constants ----------------
#define LSEQ   2048
#define DM     512
#define NLAYER 4
#define NMODE  32
#define BATCH  2
#define VOCAB  50257
#define CHUNK  32            // timesteps per scan chunk
#define NCHUNK 64            // LSEQ / CHUNK
#define ROWS   (BATCH*LSEQ)  // 4096
#define PI_F   3.14159265358979323846f

typedef __bf16 bf16_t;
typedef __bf16 bf16x8 __attribute__((ext_vector_type(8)));
typedef float  floatx4 __attribute__((ext_vector_type(4)));

__device__ __forceinline__ float gelu_f(float v) {
  // jax.nn.gelu default (approximate=True, tanh form)
  return 0.5f * v * (1.0f + tanhf(0.7978845608028654f * (v + 0.044715f * v * v * v)));
}
__device__ __forceinline__ float sigmoid_f(float v) {
  return 1.0f / (1.0f + expf(-v));
}

// ---------------- modal parameter prep ----------------
__global__ __launch_bounds__(256) void prep_kernel(
    const float* __restrict__ log_dt, const float* __restrict__ C_re,
    const float* __restrict__ C_im, float* __restrict__ wcp) {
  int idx = blockIdx.x * 256 + threadIdx.x;       // NLAYER*DM*NMODE
  int n  = idx & (NMODE - 1);
  int ld = idx >> 5;                               // layer*DM + d
  float dt = expf(log_dt[ld]);
  float ar = -0.5f * dt;
  float ai = PI_F * (float)n * dt;
  float em = expf(ar);
  float wr = em * cosf(ai), wi = em * sinf(ai);
  float pn = PI_F * (float)n;
  float inv = 1.0f / (0.25f + pn * pn);
  float m1r = wr - 1.0f, m1i = wi;
  float qr = (-0.5f * m1r + pn * m1i) * inv;       // (w-1)*conj(A)/|A|^2
  float qi = (-0.5f * m1i - pn * m1r) * inv;
  float cre = C_re[idx], cim = C_im[idx];
  float cpr = cre * qr - cim * qi;
  float cpi = cre * qi + cim * qr;
  float emT = expf(ar * (float)CHUNK);
  float aT  = ai * (float)CHUNK;
  float wTr = emT * cosf(aT), wTi = emT * sinf(aT);
  float* o = wcp + (size_t)idx * 6;
  o[0] = wr; o[1] = wi; o[2] = cpr; o[3] = cpi; o[4] = wTr; o[5] = wTi;
}

// ---------------- embedding ----------------
__global__ __launch_bounds__(256) void embed_kernel(
    const int* __restrict__ ids, const float* __restrict__ tok,
    const float* __restrict__ pos, float* __restrict__ x) {
  int idx = blockIdx.x * 256 + threadIdx.x;   // ROWS*DM
  int d  = idx & (DM - 1);
  int bl = idx >> 9;
  int l  = bl & (LSEQ - 1);
  int id = ids[bl];
  x[idx] = tok[(size_t)id * DM + d] + pos[(size_t)l * DM + d];
}

// ---------------- vectorized fp32 -> bf16 convert (8 elems/thread) ----------------
__global__ __launch_bounds__(256) void cvt8_kernel(
    const float* __restrict__ src, bf16_t* __restrict__ dst, int n8) {
  int idx8 = blockIdx.x * 256 + threadIdx.x;
  if (idx8 >= n8) return;
  int gid = idx8 * 8;
  float4 f0 = *(const float4*)(src + gid);
  float4 f1 = *(const float4*)(src + gid + 4);
  bf16x8 v;
  v[0] = (bf16_t)f0.x; v[1] = (bf16_t)f0.y; v[2] = (bf16_t)f0.z; v[3] = (bf16_t)f0.w;
  v[4] = (bf16_t)f1.x; v[5] = (bf16_t)f1.y; v[6] = (bf16_t)f1.z; v[7] = (bf16_t)f1.w;
  *(bf16x8*)(dst + gid) = v;
}

// ---------------- out_w convert with 16-group a/g row interleave ----------------
// permuted row r <- orig row hi*512 + u*16 + wi, where u=r>>5, hi=(r>>4)&1, wi=r&15.
// So permuted cols come in 16-wide pairs: frag j (even) = a_d, frag j+1 = g_d, same lane.
__global__ __launch_bounds__(256) void cvt_wperm_kernel(
    const float* __restrict__ src, bf16_t* __restrict__ dst) {
  int idx8 = blockIdx.x * 256 + threadIdx.x;      // NLAYER*1024*512/8 = 262144
  int gid = idx8 * 8;
  int layer = gid >> 19;                           // /(1024*512)
  int rem = gid & ((1 << 19) - 1);
  int r = rem >> 9;
  int c = rem & 511;
  int orig = ((r >> 4) & 1) * 512 + ((r >> 5) << 4) + (r & 15);
  const float* s = src + ((size_t)layer << 19) + ((size_t)orig << 9) + c;
  float4 f0 = *(const float4*)s;
  float4 f1 = *(const float4*)(s + 4);
  bf16x8 v;
  v[0] = (bf16_t)f0.x; v[1] = (bf16_t)f0.y; v[2] = (bf16_t)f0.z; v[3] = (bf16_t)f0.w;
  v[4] = (bf16_t)f1.x; v[5] = (bf16_t)f1.y; v[6] = (bf16_t)f1.z; v[7] = (bf16_t)f1.w;
  *(bf16x8*)(dst + gid) = v;
}

// ---------------- scan phase 1: local chunk end-states ----------------
__global__ __launch_bounds__(256) void scan_phase1_kernel(
    const float* __restrict__ x, const float* __restrict__ wcp,
    float2* __restrict__ E, int layer) {
  int idx = blockIdx.x * 256 + threadIdx.x;   // BATCH*NCHUNK*DM, d fastest
  int d  = idx & (DM - 1);
  int bc = idx >> 9;
  int c  = bc & (NCHUNK - 1);
  int b  = bc >> 6;
  const float* xp = x + ((size_t)(b * LSEQ + c * CHUNK)) * DM + d;
  float xr[CHUNK];
  #pragma unroll
  for (int t = 0; t < CHUNK; t++) xr[t] = xp[(size_t)t * DM];
  const float* wp = wcp + (size_t)(layer * DM + d) * NMODE * 6;
  float2* Ep = E + ((size_t)(b * DM + d) * NCHUNK + c) * NMODE;
  #pragma unroll 1
  for (int np = 0; np < NMODE / 2; np++) {
    int n0 = np * 2;
    float w0r = wp[n0*6+0], w0i = wp[n0*6+1];
    float w1r = wp[n0*6+6], w1i = wp[n0*6+7];
    float s0r = 0.f, s0i = 0.f, s1r = 0.f, s1i = 0.f;
    #pragma unroll
    for (int t = 0; t < CHUNK; t++) {
      float xt = xr[t];
      float a0r = fmaf(w0r, s0r, fmaf(-w0i, s0i, xt));
      float a0i = fmaf(w0r, s0i, w0i * s0r);
      float a1r = fmaf(w1r, s1r, fmaf(-w1i, s1i, xt));
      float a1i = fmaf(w1r, s1i, w1i * s1r);
      s0r = a0r; s0i = a0i; s1r = a1r; s1i = a1i;
    }
    Ep[n0]     = make_float2(s0r, s0i);
    Ep[n0 + 1] = make_float2(s1r, s1i);
  }
}

// ---------------- scan combine: exclusive prefix across chunks ----------------
__global__ __launch_bounds__(256) void scan_combine_kernel(
    const float* __restrict__ wcp, float2* __restrict__ E, int layer) {
  int idx = blockIdx.x * 256 + threadIdx.x;   // BATCH*DM*NMODE, n fastest
  int n  = idx & (NMODE - 1);
  int bd = idx >> 5;                           // b*DM + d
  int d  = bd & (DM - 1);
  const float* wp = wcp + ((size_t)(layer * DM + d) * NMODE + n) * 6;
  float wTr = wp[4], wTi = wp[5];
  float2* Ep = E + (size_t)bd * NCHUNK * NMODE + n;
  float sr = 0.f, si = 0.f;
  for (int c = 0; c < NCHUNK; c++) {
    float2 e = Ep[(size_t)c * NMODE];
    Ep[(size_t)c * NMODE] = make_float2(sr, si);
    float tr = fmaf(wTr, sr, -(wTi * si)) + e.x;
    float ti = fmaf(wTr, si, wTi * sr) + e.y;
    sr = tr; si = ti;
  }
}

// ---------------- scan phase 2: outputs + skip + gelu -> bf16 ----------------
__global__ __launch_bounds__(256) void scan_phase2_kernel(
    const float* __restrict__ x, const float* __restrict__ wcp,
    const float2* __restrict__ E, const float* __restrict__ skipD,
    bf16_t* __restrict__ yb, int layer) {
  int idx = blockIdx.x * 256 + threadIdx.x;   // BATCH*NCHUNK*DM, d fastest
  int d  = idx & (DM - 1);
  int bc = idx >> 9;
  int c  = bc & (NCHUNK - 1);
  int b  = bc >> 6;
  const float* xp = x + ((size_t)(b * LSEQ + c * CHUNK)) * DM + d;
  float xr[CHUNK];
  #pragma unroll
  for (int t = 0; t < CHUNK; t++) xr[t] = xp[(size_t)t * DM];
  float ya[CHUNK];
  #pragma unroll
  for (int t = 0; t < CHUNK; t++) ya[t] = 0.f;
  const float* wp = wcp + (size_t)(layer * DM + d) * NMODE * 6;
  const float2* Ep = E + ((size_t)(b * DM + d) * NCHUNK + c) * NMODE;
  #pragma unroll 1
  for (int np = 0; np < NMODE / 2; np++) {
    int n0 = np * 2;
    float w0r = wp[n0*6+0], w0i = wp[n0*6+1];
    float c0r = wp[n0*6+2], c0i = wp[n0*6+3];
    float w1r = wp[n0*6+6], w1i = wp[n0*6+7];
    float c1r = wp[n0*6+8], c1i = wp[n0*6+9];
    float2 e0 = Ep[n0], e1 = Ep[n0 + 1];
    float s0r = e0.x, s0i = e0.y, s1r = e1.x, s1i = e1.y;
    #pragma unroll
    for (int t = 0; t < CHUNK; t++) {
      float xt = xr[t];
      float a0r = fmaf(w0r, s0r, fmaf(-w0i, s0i, xt));
      float a0i = fmaf(w0r, s0i, w0i * s0r);
      float a1r = fmaf(w1r, s1r, fmaf(-w1i, s1i, xt));
      float a1i = fmaf(w1r, s1i, w1i * s1r);
      s0r = a0r; s0i = a0i; s1r = a1r; s1i = a1i;
      float acc = fmaf(c0r, s0r, ya[t]);
      acc = fmaf(-c0i, s0i, acc);
      acc = fmaf(c1r, s1r, acc);
      ya[t] = fmaf(-c1i, s1i, acc);
    }
  }
  float sk = skipD[layer * DM + d];
  bf16_t* yp = yb + ((size_t)(b * LSEQ + c * CHUNK)) * DM + d;
  #pragma unroll
  for (int t = 0; t < CHUNK; t++) {
    float v = fmaf(xr[t], sk, 2.0f * ya[t]);
    yp[(size_t)t * DM] = (bf16_t)gelu_f(v);
  }
}

// ---------------- GEMM1 + GLU + residual (m97 128x128 structure) ----------------
// A(4096,512) bf16 * Bperm(1024,512)^T; fragment pairs (j even, j+1) hold a_d / g_d
// for the SAME lane (16-group row interleave in cvt_wperm). Epilogue does
// x += (a+ba) * sigmoid(g+bg) directly -- no z buffer, no separate GLU kernel.
__global__ __launch_bounds__(256) void gemm1_glu_kernel(
    const bf16_t* __restrict__ A, const bf16_t* __restrict__ B,
    const float* __restrict__ bias2, float* __restrict__ x) {
  __shared__ __align__(16) bf16_t As[128 * 32];
  __shared__ __align__(16) bf16_t Bs[128 * 32];
  int tid = threadIdx.x;
  int lid = tid & 63;
  int w   = tid >> 6;
  int tileM = blockIdx.y * 128;
  int tileN = blockIdx.x * 128;
  int wm = w & 1, wn = w >> 1;

  floatx4 acc[4][4];
  floatx4 zero = {0.f, 0.f, 0.f, 0.f};
  #pragma unroll
  for (int i = 0; i < 4; i++)
    #pragma unroll
    for (int j = 0; j < 4; j++) acc[i][j] = zero;

  for (int k0 = 0; k0 < DM; k0 += 32) {
    #pragma unroll
    for (int i = 0; i < 2; i++) {
      int flat = i * 256 + tid;
      int row  = flat >> 2;
      int kg   = (flat & 3) * 8;
      const bf16_t* ga = A + (size_t)(tileM + row) * DM + (k0 + kg);
      const bf16_t* gb = B + (size_t)(tileN + row) * DM + (k0 + kg);
      __builtin_amdgcn_global_load_lds(
          (const __attribute__((address_space(1))) void*)ga,
          (__attribute__((address_space(3))) void*)(&As[flat * 8]), 16, 0, 0);
      __builtin_amdgcn_global_load_lds(
          (const __attribute__((address_space(1))) void*)gb,
          (__attribute__((address_space(3))) void*)(&Bs[flat * 8]), 16, 0, 0);
    }
    __syncthreads();

    bf16x8 af[4], bfr[4];
    #pragma unroll
    for (int i = 0; i < 4; i++) {
      af[i]  = *(const bf16x8*)&As[((wm * 64 + i * 16 + (lid & 15)) * 32) + ((lid >> 4) * 8)];
      bfr[i] = *(const bf16x8*)&Bs[((wn * 64 + i * 16 + (lid & 15)) * 32) + ((lid >> 4) * 8)];
    }
    #pragma unroll
    for (int i = 0; i < 4; i++)
      #pragma unroll
      for (int j = 0; j < 4; j++)
        acc[i][j] = __builtin_amdgcn_mfma_f32_16x16x32_bf16(af[i], bfr[j], acc[i][j], 0, 0, 0);
    __syncthreads();
  }

  // epilogue: pair frags (j, j+1): a/g for d = (n0>>5)*16 + (lane&15)
  #pragma unroll
  for (int i = 0; i < 4; i++) {
    int m = tileM + wm * 64 + i * 16 + (lid >> 4) * 4;
    #pragma unroll
    for (int j = 0; j < 4; j += 2) {
      int n0 = tileN + wn * 64 + j * 16;
      int d  = ((n0 >> 5) << 4) + (lid & 15);
      float ba = bias2[d], bg = bias2[512 + d];
      #pragma unroll
      for (int r = 0; r < 4; r++) {
        float a = acc[i][j][r] + ba;
        float g = acc[i][j + 1][r] + bg;
        size_t xi = (size_t)(m + r) * DM + d;
        x[xi] += a * sigmoid_f(g);
      }
    }
  }
}

// ---------------- head GEMM: 256x256 tile, BK=64, 8 waves, 1-barrier prefetch ----
// C(M,Nreal) = A(M,512) * B(Nreal,512)^T.  2x arithmetic intensity vs 128^2
// (128 FLOP/staged byte), next-tile global_load_lds issued BEFORE current tile's
// ds_read+MFMA so the __syncthreads vmcnt drain lands after a full MFMA phase
// (needed: 128KB LDS -> 1 block/CU, no sibling-block overlap). Named double
// buffers (As0/As1) keep LDS alias analysis exact. Bijective XCD swizzle with
// M-fastest order: 16 consecutive wgids share one 256KB B panel (L2 reuse).
__global__ __launch_bounds__(512, 2) void gemm_head_kernel(
    const bf16_t* __restrict__ A, const bf16_t* __restrict__ B,
    float* __restrict__ C, int Nreal) {
  __shared__ __align__(16) bf16_t As0[256 * 64];
  __shared__ __align__(16) bf16_t Bs0[256 * 64];
  __shared__ __align__(16) bf16_t As1[256 * 64];
  __shared__ __align__(16) bf16_t Bs1[256 * 64];
  const int K = DM;  // 512
  int tid = threadIdx.x;
  int lid = tid & 63;
  int w   = tid >> 6;            // 0..7
  int wm  = w >> 2, wn = w & 3;  // 2 x 4 wave grid; wave tile 128x64

  // bijective XCD swizzle (m204 formula), then M-fastest tile order
  int nwg = gridDim.x;
  int bid = blockIdx.x;
  int xcd = bid & 7, lin = bid >> 3;
  int q = nwg >> 3, rq = nwg & 7;
  int wgid = (xcd < rq ? xcd * (q + 1) : rq * (q + 1) + (xcd - rq) * q) + lin;
  int tileM = (wgid & 15) * 256;   // M=4096 -> 16 tiles, fastest
  int tileN = (wgid >> 4) * 256;

  floatx4 acc[8][4];
  floatx4 zero = {0.f, 0.f, 0.f, 0.f};
  #pragma unroll
  for (int i = 0; i < 8; i++)
    #pragma unroll
    for (int j = 0; j < 4; j++) acc[i][j] = zero;

  auto STAGE = [&](bf16_t* as, bf16_t* bs, int k0) {
    #pragma unroll
    for (int i = 0; i < 4; i++) {
      int flat = i * 512 + tid;      // 0..2047
      int row  = flat >> 3;          // 0..255
      int kg   = (flat & 7) * 8;     // 0..56
      const bf16_t* ga = A + (size_t)(tileM + row) * K + (k0 + kg);
      int brow = tileN + row;
      if (brow >= Nreal) brow = Nreal - 1;   // clamp; store predicate discards
      const bf16_t* gb = B + (size_t)brow * K + (k0 + kg);
      __builtin_amdgcn_global_load_lds(
          (const __attribute__((address_space(1))) void*)ga,
          (__attribute__((address_space(3))) void*)(&as[flat * 8]), 16, 0, 0);
      __builtin_amdgcn_global_load_lds(
          (const __attribute__((address_space(1))) void*)gb,
          (__attribute__((address_space(3))) void*)(&bs[flat * 8]), 16, 0, 0);
    }
  };

  auto COMPUTE = [&](const bf16_t* as, const bf16_t* bs) {
    #pragma unroll
    for (int ks = 0; ks < 2; ks++) {
      bf16x8 af[8], bfr[4];
      #pragma unroll
      for (int i = 0; i < 8; i++)
        af[i] = *(const bf16x8*)&as[(wm * 128 + i * 16 + (lid & 15)) * 64 + ks * 32 + (lid >> 4) * 8];
      #pragma unroll
      for (int j = 0; j < 4; j++)
        bfr[j] = *(const bf16x8*)&bs[(wn * 64 + j * 16 + (lid & 15)) * 64 + ks * 32 + (lid >> 4) * 8];
      __builtin_amdgcn_s_setprio(1);
      #pragma unroll
      for (int i = 0; i < 8; i++)
        #pragma unroll
        for (int j = 0; j < 4; j++)
          acc[i][j] = __builtin_amdgcn_mfma_f32_16x16x32_bf16(af[i], bfr[j], acc[i][j], 0, 0, 0);
      __builtin_amdgcn_s_setprio(0);
    }
  };

  const int nt = K >> 6;   // 8 K-tiles of 64
  STAGE(As0, Bs0, 0);
  __syncthreads();         // drains vmcnt(0): tile 0 resident
  #pragma unroll 1
  for (int t = 0; t < nt; t += 2) {
    if (t + 1 < nt) STAGE(As1, Bs1, (t + 1) << 6);
    COMPUTE(As0, Bs0);
    __syncthreads();       // tile t+1 resident; all waves done with As0/Bs0
    if (t + 1 < nt) {
      if (t + 2 < nt) STAGE(As0, Bs0, (t + 2) << 6);
      COMPUTE(As1, Bs1);
      __syncthreads();
    }
  }

  // C/D layout: col = lane&15 (N dim), row = (lane>>4)*4 + reg (M dim)
  #pragma unroll
  for (int i = 0; i < 8; i++) {
    int m = tileM + wm * 128 + i * 16 + (lid >> 4) * 4;
    #pragma unroll
    for (int j = 0; j < 4; j++) {
      int n = tileN + wn * 64 + j * 16 + (lid & 15);
      if (n < Nreal) {
        #pragma unroll
        for (int r = 0; r < 4; r++)
          C[(size_t)(m + r) * Nreal + n] = acc[i][j][r];
      }
    }
  }
}

// ---------------- LayerNorm -> bf16 ----------------
__global__ __launch_bounds__(256) void ln_kernel(
    const float* __restrict__ x, const float* __restrict__ g,
    const float* __restrict__ bta, bf16_t* __restrict__ xn) {
  int m = blockIdx.x;
  int tid = threadIdx.x;
  int lid = tid & 63, w = tid >> 6;
  const float* xp = x + (size_t)m * DM;
  float v0 = xp[tid], v1 = xp[tid + 256];
  __shared__ float sw[4];
  __shared__ float bcast;
  float s = v0 + v1;
  #pragma unroll
  for (int o = 32; o > 0; o >>= 1) s += __shfl_down(s, o);
  if (lid == 0) sw[w] = s;
  __syncthreads();
  if (tid == 0) bcast = (sw[0] + sw[1] + sw[2] + sw[3]) * (1.0f / DM);
  __syncthreads();
  float mu = bcast;
  float d0 = v0 - mu, d1 = v1 - mu;
  float qq = d0 * d0 + d1 * d1;
  #pragma unroll
  for (int o = 32; o > 0; o >>= 1) qq += __shfl_down(qq, o);
  __syncthreads();
  if (lid == 0) sw[w] = qq;
  __syncthreads();
  if (tid == 0) bcast = rsqrtf((sw[0] + sw[1] + sw[2] + sw[3]) * (1.0f / DM) + 1e-5f);
  __syncthreads();
  float rs = bcast;
  xn[(size_t)m * DM + tid]       = (bf16_t)(d0 * rs * g[tid] + bta[tid]);
  xn[(size_t)m * DM + tid + 256] = (bf16_t)(d1 * rs * g[tid + 256] + bta[tid + 256]);
}

// ---------------- launch ----------------
extern "C" void kernel_launch(void* const* d_in, const int* in_sizes, int n_in,
                              void* d_out, int out_size, void* d_ws, size_t ws_size,
                              hipStream_t stream) {
  const int*   ids   = (const int*)  d_in[0];
  const float* tok   = (const float*)d_in[1];
  const float* pos   = (const float*)d_in[2];
  const float* logdt = (const float*)d_in[3];
  const float* cre   = (const float*)d_in[4];
  const float* cim   = (const float*)d_in[5];
  const float* skipD = (const float*)d_in[6];
  const float* outw  = (const float*)d_in[7];
  const float* outb  = (const float*)d_in[8];
  const float* lng   = (const float*)d_in[9];
  const float* lnb   = (const float*)d_in[10];
  const float* headw = (const float*)d_in[11];
  float* logits = (float*)d_out;

  // workspace layout:
  //  [0,8M)     x residual stream (fp32, 8MB)
  //  [8M,24M)   E scan states (float2, 16MB exactly)
  //  [24M,28M)  yb bf16 GEMM1 input  ALIASES  xn bf16 head-GEMM input (4MB)
  //  [28M,32M)  wbp: out_w bf16, 16-group a/g row-permuted (4MB)
  //  [32M,34M)  wcp modal params (1.5MB)
  //  [34M,~86M) hb: head_w bf16
  char* ws = (char*)d_ws;
  float*  x   = (float*)(ws);
  float2* E   = (float2*)(ws + (8u  << 20));
  bf16_t* yb  = (bf16_t*)(ws + (24u << 20));
  bf16_t* xn  = (bf16_t*)(ws + (24u << 20));
  bf16_t* wbp = (bf16_t*)(ws + (28u << 20));
  float*  wcp = (float*)(ws + (32u << 20));
  bf16_t* hb  = (bf16_t*)(ws + (34u << 20));

  prep_kernel<<<(NLAYER * DM * NMODE) / 256, 256, 0, stream>>>(logdt, cre, cim, wcp);
  cvt_wperm_kernel<<<(NLAYER * 2 * DM * DM / 8) / 256, 256, 0, stream>>>(outw, wbp);
  int n8 = (VOCAB * DM) / 8;   // divisible: 512 % 8 == 0
  cvt8_kernel<<<(n8 + 255) / 256, 256, 0, stream>>>(headw, hb, n8);
  embed_kernel<<<(ROWS * DM) / 256, 256, 0, stream>>>(ids, tok, pos, x);

  for (int layer = 0; layer < NLAYER; layer++) {
    scan_phase1_kernel<<<(BATCH * NCHUNK * DM) / 256, 256, 0, stream>>>(x, wcp, E, layer);
    scan_combine_kernel<<<(BATCH * DM * NMODE) / 256, 256, 0, stream>>>(wcp, E, layer);
    scan_phase2_kernel<<<(BATCH * NCHUNK * DM) / 256, 256, 0, stream>>>(x, wcp, E, skipD, yb, layer);
    dim3 g1((2 * DM) / 128, ROWS / 128);
    gemm1_glu_kernel<<<g1, 256, 0, stream>>>(yb, wbp + (size_t)layer * 2 * DM * DM,
                                             outb + layer * 2 * DM, x);
  }

  ln_kernel<<<ROWS, 256, 0, stream>>>(x, lng, lnb, xn);
  int ntn = (VOCAB + 255) / 256;           // 197 N-tiles
  gemm_head_kernel<<<16 * ntn, 512, 0, stream>>>(xn, hb, logits, VOCAB);
}